// Round 7
// baseline (110.351 us; speedup 1.0000x reference)
//
#include <hip/hip_runtime.h>
#include <hip/hip_bf16.h>

#define BB 8
#define FF 4096
#define SS 1024
#define DD 128
#define DLL 256
#define NF (BB*FF)     // 32768 facts
#define NMSG (2*NF)    // 65536 message slots
#define NNODE (BB*SS)  // 8192 (b,s) rows
#define FPB 16         // facts per msg block (32 messages) -> grid 2048
#define CAP 36         // bucket capacity per node (lambda~7; P(>36) ~ 1e-18)

typedef short  short8 __attribute__((ext_vector_type(8)));
typedef float  f32x4  __attribute__((ext_vector_type(4)));

__device__ __forceinline__ ushort f2bf(float x) {
    uint u = __float_as_uint(x);
    uint r = (u + 0x7fffu + ((u >> 16) & 1u)) >> 16;
    return (ushort)r;
}
__device__ __forceinline__ float bf2f(uint lo16) {
    return __uint_as_float(lo16 << 16);
}

// gelu(x) = 0.5x(1+erf(x/sqrt2)); erf via A&S 7.1.26, |err|<=1.5e-7, branchless.
__device__ __forceinline__ float gelu_fast(float x) {
    const float z = fabsf(x) * 0.70710678118654752440f;
    const float t = __builtin_amdgcn_rcpf(__builtin_fmaf(0.3275911f, z, 1.0f));
    float p = 1.061405429f;
    p = __builtin_fmaf(p, t, -1.453152027f);
    p = __builtin_fmaf(p, t, 1.421413741f);
    p = __builtin_fmaf(p, t, -0.284496736f);
    p = __builtin_fmaf(p, t, 0.254829592f);
    p *= t;
    const float e = __expf(-z * z);
    const float erfv = __builtin_fmaf(-p, e, 1.0f);
    return 0.5f * x * (1.0f + copysignf(erfv, x));
}

// ---------------------------------------------------------------------------
// Prep: w1T/w2T bf16 transpose + zero cnt + zero pooled (replaces memset).
// ---------------------------------------------------------------------------
#define N_W1 (384*256)
#define N_W2 (256*128)
#define N_PREP (N_W1 + N_W2 + NNODE + BB*DD)   // 140288

__global__ __launch_bounds__(256) void prep_kernel(
    const float* __restrict__ w1, const float* __restrict__ w2,
    ushort* __restrict__ w1T, ushort* __restrict__ w2T,
    int* __restrict__ cnt, float* __restrict__ pooled)
{
    int i = blockIdx.x * 256 + threadIdx.x;
    if (i < N_W1) { int k = i >> 8, n = i & 255; w1T[n*384 + k] = f2bf(w1[i]); return; }
    i -= N_W1;
    if (i < N_W2) { int k = i >> 7, d = i & 127; w2T[d*256 + k] = f2bf(w2[i]); return; }
    i -= N_W2;
    if (i < NNODE) { cnt[i] = 0; return; }
    i -= NNODE;
    if (i < BB*DD) pooled[i] = 0.0f;
}

// ---------------------------------------------------------------------------
// msg kernel: 16 facts / 32 messages per block, 4 waves, LDS 16 KB.
// Wave tile GEMM1: 64 n-cols x 32 msgs (acc[4][2]); GEMM2: 32 d x 32 msgs.
// Also builds the node->msg bucket index (first 32 threads).
// Plain coalesced bf16 stores of message rows (no atomics).
// ---------------------------------------------------------------------------
__global__ __launch_bounds__(256, 8) void msg_kernel(
    const int* __restrict__ a0, const int* __restrict__ a1,
    const int* __restrict__ pidx, const float* __restrict__ bidir,
    const float* __restrict__ pos_emb, const float* __restrict__ pred_emb,
    const ushort* __restrict__ w1T, const float* __restrict__ b1,
    const ushort* __restrict__ w2T, const float* __restrict__ b2,
    ushort* __restrict__ msgbuf, int* __restrict__ cnt, ushort* __restrict__ idx16)
{
    __shared__ uint4 shm[1024];           // 16 KB union: xs (768 u4) / h1 (1024 u4)

    const int tid = threadIdx.x;
    const int fbase = blockIdx.x * FPB;
    const int wid = tid >> 6, lane = tid & 63;
    const int lq = lane >> 4, lr = lane & 15;
    const int factL = lr >> 1, par = lr & 1;

    // ---- bucket build: one thread per message of this block ----
    if (tid < 2 * FPB) {
        const int i = blockIdx.x * (2 * FPB) + tid;    // global msg slot
        const int g = i >> 1, p = i & 1;
        const float w = p ? bidir[g] : 1.0f;
        if (w != 0.0f) {
            const int nid = ((g >> 12) << 10) + (p ? a0[g] : a1[g]);
            const int slot = atomicAdd(&cnt[nid], 1);
            if (slot < CAP) idx16[nid * CAP + slot] = (ushort)i;
        }
    }

    // ---- stage gathered inputs: fp32 load -> bf16 pack -> LDS (swizzled) ----
    #pragma unroll
    for (int it = 0; it < 3; ++it) {
        const int U = tid + it * 256;
        const int f = U / 48, u = U - 48 * f;
        const int seg = u >> 4, du = u & 15;
        const int g = fbase + f;
        const int row = (seg == 0) ? a0[g] : ((seg == 1) ? pidx[g] : a1[g]);
        const float* src = ((seg == 1) ? pred_emb : pos_emb) + row * DD + du * 8;
        const float4 x0 = *(const float4*)src;
        const float4 x1 = *(const float4*)(src + 4);
        uint4 t;
        t.x = (uint)f2bf(x0.x) | ((uint)f2bf(x0.y) << 16);
        t.y = (uint)f2bf(x0.z) | ((uint)f2bf(x0.w) << 16);
        t.z = (uint)f2bf(x1.x) | ((uint)f2bf(x1.y) << 16);
        t.w = (uint)f2bf(x1.z) | ((uint)f2bf(x1.w) << 16);
        shm[f * 48 + (u ^ (f & 7))] = t;
    }
    __syncthreads();

    // ---- GEMM1: D1[n][m], acc[nf][mf]; n = wid*64 + nf*16 + (lq*4 + r) ----
    f32x4 acc[4][2];
    #pragma unroll
    for (int nf = 0; nf < 4; ++nf)
        #pragma unroll
        for (int mf = 0; mf < 2; ++mf) acc[nf][mf] = (f32x4)0.0f;

    for (int ks = 0; ks < 12; ++ks) {
        const int k_el = ks * 32 + lq * 8;
        const int seg = ks >> 2;
        const int kp = k_el + (par ? (seg == 0 ? 256 : (seg == 2 ? -256 : 0)) : 0);
        const int uq = (kp >> 3) ^ factL;
        short8 xfrag[2];
        #pragma unroll
        for (int mf = 0; mf < 2; ++mf)
            xfrag[mf] = *(const short8*)&shm[(mf * 8 + factL) * 48 + uq];
        short8 wfrag[4];
        #pragma unroll
        for (int nf = 0; nf < 4; ++nf)
            wfrag[nf] = *(const short8*)(w1T + (wid * 64 + nf * 16 + lr) * 384 + k_el);
        #pragma unroll
        for (int nf = 0; nf < 4; ++nf)
            #pragma unroll
            for (int mf = 0; mf < 2; ++mf)
                acc[nf][mf] = __builtin_amdgcn_mfma_f32_16x16x32_bf16(wfrag[nf], xfrag[mf], acc[nf][mf], 0, 0, 0);
    }
    __syncthreads();   // xs dead; reuse LDS as h1[32][256] bf16 (swizzled)

    // ---- bias + gelu + packed h1 store (ds_write_b64) ----
    #pragma unroll
    for (int nf = 0; nf < 4; ++nf) {
        const float4 bj = *(const float4*)(b1 + wid * 64 + nf * 16 + lq * 4);
        #pragma unroll
        for (int mf = 0; mf < 2; ++mf) {
            const int m = mf * 16 + lr;
            uint2 t;
            t.x = (uint)f2bf(gelu_fast(acc[nf][mf][0] + bj.x)) |
                  ((uint)f2bf(gelu_fast(acc[nf][mf][1] + bj.y)) << 16);
            t.y = (uint)f2bf(gelu_fast(acc[nf][mf][2] + bj.z)) |
                  ((uint)f2bf(gelu_fast(acc[nf][mf][3] + bj.w)) << 16);
            const int col = wid * 128 + nf * 32 + lq * 8;   // byte col within 512B row
            const int byteoff = m * 512 + (((col >> 4) ^ (m & 15)) << 4) + (col & 15);
            *(uint2*)((char*)shm + byteoff) = t;
        }
    }
    __syncthreads();

    // ---- GEMM2: D2[d][m], acc2[nf][mf]; d = wid*32 + nf*16 + (lq*4 + r) ----
    f32x4 acc2[2][2];
    #pragma unroll
    for (int nf = 0; nf < 2; ++nf)
        #pragma unroll
        for (int mf = 0; mf < 2; ++mf) acc2[nf][mf] = (f32x4)0.0f;

    for (int ks = 0; ks < 8; ++ks) {
        short8 hfrag[2];
        #pragma unroll
        for (int mf = 0; mf < 2; ++mf) {
            const int m = mf * 16 + lr;
            hfrag[mf] = *(const short8*)((char*)shm + m * 512 + ((((ks * 4 + lq)) ^ (m & 15)) << 4));
        }
        short8 w2frag[2];
        #pragma unroll
        for (int nf = 0; nf < 2; ++nf)
            w2frag[nf] = *(const short8*)(w2T + (wid * 32 + nf * 16 + lr) * 256 + ks * 32 + lq * 8);
        #pragma unroll
        for (int nf = 0; nf < 2; ++nf)
            #pragma unroll
            for (int mf = 0; mf < 2; ++mf)
                acc2[nf][mf] = __builtin_amdgcn_mfma_f32_16x16x32_bf16(w2frag[nf], hfrag[mf], acc2[nf][mf], 0, 0, 0);
    }

    // ---- epilogue: bias + bidir weight + plain bf16 stores (8B/lane) ----
    {
        float wgt_[2];
        #pragma unroll
        for (int mf = 0; mf < 2; ++mf) {
            const int g = fbase + mf * 8 + factL;
            wgt_[mf] = par ? bidir[g] : 1.0f;
        }
        #pragma unroll
        for (int nf = 0; nf < 2; ++nf) {
            const float4 bd = *(const float4*)(b2 + wid * 32 + nf * 16 + lq * 4);
            const int d0 = wid * 32 + nf * 16 + lq * 4;
            #pragma unroll
            for (int mf = 0; mf < 2; ++mf) {
                const int m = mf * 16 + lr;
                const float w = wgt_[mf];
                if (w != 0.0f) {
                    uint2 t;
                    t.x = (uint)f2bf((acc2[nf][mf][0] + bd.x) * w) |
                          ((uint)f2bf((acc2[nf][mf][1] + bd.y) * w) << 16);
                    t.y = (uint)f2bf((acc2[nf][mf][2] + bd.z) * w) |
                          ((uint)f2bf((acc2[nf][mf][3] + bd.w) * w) << 16);
                    *(uint2*)(msgbuf + (size_t)(fbase * 2 + m) * DD + d0) = t;
                }
            }
        }
    }
}

// ---------------------------------------------------------------------------
// Fused bucket-gather + LayerNorm + pool.  One wave per node, 4 nodes/block.
// ---------------------------------------------------------------------------
__global__ __launch_bounds__(256) void reduce_kernel(
    const float* __restrict__ pos_emb, const ushort* __restrict__ msgbuf,
    const int* __restrict__ cnt, const ushort* __restrict__ idx16,
    const float* __restrict__ ln_g, const float* __restrict__ ln_b,
    float* __restrict__ pooled)
{
    const int wave = threadIdx.x >> 6, lane = threadIdx.x & 63;
    const int nid = blockIdx.x * 4 + wave;
    const int s = nid & (SS - 1);
    const int b = (blockIdx.x * 4) >> 10;

    float2 h = *(const float2*)(pos_emb + s * DD + 2 * lane);
    int c = cnt[nid]; if (c > CAP) c = CAP;
    const ushort* bucket = idx16 + nid * CAP;
    for (int j = 0; j < c; ++j) {
        const uint mid = bucket[j];
        const uint u = *(const uint*)(msgbuf + (size_t)mid * DD + 2 * lane);
        h.x += bf2f(u & 0xffffu);
        h.y += bf2f(u >> 16);
    }

    float sum = h.x + h.y;
    #pragma unroll
    for (int o = 32; o > 0; o >>= 1) sum += __shfl_xor(sum, o);
    const float mu = sum * (1.0f / 128.0f);
    const float d0 = h.x - mu, d1 = h.y - mu;
    float sq = d0 * d0 + d1 * d1;
    #pragma unroll
    for (int o = 32; o > 0; o >>= 1) sq += __shfl_xor(sq, o);
    const float rstd = rsqrtf(sq * (1.0f / 128.0f) + 1e-5f);

    const float2 g2  = *(const float2*)(ln_g + 2 * lane);
    const float2 bb2 = *(const float2*)(ln_b + 2 * lane);
    const float p0 = d0 * rstd * g2.x + bb2.x;
    const float p1 = d1 * rstd * g2.y + bb2.y;

    __shared__ float red[4][128];
    red[wave][2 * lane]     = p0;
    red[wave][2 * lane + 1] = p1;
    __syncthreads();
    if (threadIdx.x < 128) {
        const float v = red[0][threadIdx.x] + red[1][threadIdx.x]
                      + red[2][threadIdx.x] + red[3][threadIdx.x];
        atomicAdd(&pooled[b * DD + threadIdx.x], v);
    }
}

// ---------------------------------------------------------------------------
// Latent head
// ---------------------------------------------------------------------------
__global__ __launch_bounds__(256) void head_kernel(
    const float* __restrict__ pooled,
    const float* __restrict__ lw1, const float* __restrict__ lb1,
    const float* __restrict__ lw2, const float* __restrict__ lb2,
    float* __restrict__ out)
{
    const int b = blockIdx.x;
    const int j = threadIdx.x;
    __shared__ float p[128];
    __shared__ float t1[256];
    if (j < 128) p[j] = pooled[b*DD + j] * (1.0f / (float)SS);
    __syncthreads();
    float acc = lb1[j];
    for (int k = 0; k < 128; ++k) acc += p[k] * lw1[k*256 + j];
    t1[j] = gelu_fast(acc);
    __syncthreads();
    float acc2 = lb2[j];
    for (int k = 0; k < 256; ++k) acc2 += t1[k] * lw2[k*256 + j];
    out[b*DLL + j] = acc2;
}

extern "C" void kernel_launch(void* const* d_in, const int* in_sizes, int n_in,
                              void* d_out, int out_size, void* d_ws, size_t ws_size,
                              hipStream_t stream) {
    const int*   a0       = (const int*)d_in[0];
    const int*   a1       = (const int*)d_in[1];
    const int*   pidx     = (const int*)d_in[2];
    const float* bidir    = (const float*)d_in[3];
    const float* pos_emb  = (const float*)d_in[4];
    const float* pred_emb = (const float*)d_in[5];
    const float* w1       = (const float*)d_in[6];
    const float* b1       = (const float*)d_in[7];
    const float* w2       = (const float*)d_in[8];
    const float* b2       = (const float*)d_in[9];
    const float* ln_g     = (const float*)d_in[10];
    const float* ln_b     = (const float*)d_in[11];
    const float* lw1      = (const float*)d_in[12];
    const float* lb1      = (const float*)d_in[13];
    const float* lw2      = (const float*)d_in[14];
    const float* lb2      = (const float*)d_in[15];

    char* ws = (char*)d_ws;
    const size_t O_MSG  = 0;                             // 16 MB (NMSG*128 bf16)
    const size_t O_CNT  = 16777216;                      // 32 KB (int[NNODE])
    const size_t O_POOL = O_CNT + 32768;                 // 4 KB  (fp32[B*D])
    const size_t O_IDX  = O_POOL + 4096;                 // 576 KB (NNODE*CAP u16)
    const size_t O_W1T  = O_IDX + (size_t)NNODE*CAP*2;   // 192 KB
    const size_t O_W2T  = O_W1T + 196608;                // 64 KB

    ushort* msgbuf = (ushort*)(ws + O_MSG);
    int*    cnt    = (int*)(ws + O_CNT);
    float*  pooled = (float*)(ws + O_POOL);
    ushort* idx16  = (ushort*)(ws + O_IDX);
    ushort* w1T    = (ushort*)(ws + O_W1T);
    ushort* w2T    = (ushort*)(ws + O_W2T);

    prep_kernel<<<(N_PREP + 255) / 256, 256, 0, stream>>>(
        w1, w2, w1T, w2T, cnt, pooled);
    msg_kernel<<<NF / FPB, 256, 0, stream>>>(a0, a1, pidx, bidir,
        pos_emb, pred_emb, w1T, b1, w2T, b2, msgbuf, cnt, idx16);
    reduce_kernel<<<NNODE / 4, 256, 0, stream>>>(
        pos_emb, msgbuf, cnt, idx16, ln_g, ln_b, pooled);
    head_kernel<<<BB, 256, 0, stream>>>(pooled, lw1, lb1, lw2, lb2, (float*)d_out);
}

// Round 8
// 70.375 us; speedup vs baseline: 1.5680x; 1.5680x over previous
//
#include <hip/hip_runtime.h>
#include <hip/hip_bf16.h>

#define BB 8
#define FF 4096
#define SS 1024
#define DD 128
#define DLL 256
#define NF (BB*FF)     // 32768 facts
#define NMSG (2*NF)    // 65536 message slots
#define NNODE (BB*SS)  // 8192 (b,s) rows
#define FPB 32         // facts per msg block (64 messages)
#define CAP 36         // bucket capacity per node (lambda~6; P(overflow) ~ 1e-11)

typedef short  short8 __attribute__((ext_vector_type(8)));
typedef float  f32x4  __attribute__((ext_vector_type(4)));

__device__ __forceinline__ uint f2bf(float x) {
    uint u = __float_as_uint(x);
    return (u + 0x7fffu + ((u >> 16) & 1u)) >> 16;
}
__device__ __forceinline__ float bf2f(uint lo16) {
    return __uint_as_float(lo16 << 16);
}

// gelu(x) = 0.5x(1+erf(x/sqrt2)); erf via A&S 7.1.26, |err|<=1.5e-7, branchless.
__device__ __forceinline__ float gelu_fast(float x) {
    const float z = fabsf(x) * 0.70710678118654752440f;
    const float t = __builtin_amdgcn_rcpf(__builtin_fmaf(0.3275911f, z, 1.0f));
    float p = 1.061405429f;
    p = __builtin_fmaf(p, t, -1.453152027f);
    p = __builtin_fmaf(p, t, 1.421413741f);
    p = __builtin_fmaf(p, t, -0.284496736f);
    p = __builtin_fmaf(p, t, 0.254829592f);
    p *= t;
    const float e = __expf(-z * z);
    const float erfv = __builtin_fmaf(-p, e, 1.0f);
    return 0.5f * x * (1.0f + copysignf(erfv, x));
}

// ---------------------------------------------------------------------------
// Prep: fragment-packed bf16 weights + zero cnt + zero pooled.
// w1p layout: frag chunk for (n0,ks) is 512 ushorts; lane slot = lr*32+lq*8.
// ---------------------------------------------------------------------------
#define N_W1 (384*256)
#define N_W2 (256*128)
#define N_PREP (N_W1 + N_W2 + NNODE + BB*DD)

__global__ __launch_bounds__(256) void prep_kernel(
    const float* __restrict__ w1, const float* __restrict__ w2,
    ushort* __restrict__ w1p, ushort* __restrict__ w2p,
    int* __restrict__ cnt, float* __restrict__ pooled)
{
    int i = blockIdx.x * 256 + threadIdx.x;
    if (i < N_W1) {   // i = k*256 + n
        const int k = i >> 8, n = i & 255;
        const int n0 = n >> 4, lr = n & 15, ks = k >> 5, lq = (k >> 3) & 3, e = k & 7;
        w1p[(n0*12 + ks)*512 + lr*32 + lq*8 + e] = (ushort)f2bf(w1[i]);
        return;
    }
    i -= N_W1;
    if (i < N_W2) {   // i = k*128 + d
        const int k = i >> 7, d = i & 127;
        const int d0 = d >> 4, lr = d & 15, ks = k >> 5, lq = (k >> 3) & 3, e = k & 7;
        w2p[(d0*8 + ks)*512 + lr*32 + lq*8 + e] = (ushort)f2bf(w2[i]);
        return;
    }
    i -= N_W2;
    if (i < NNODE) { cnt[i] = 0; return; }
    i -= NNODE;
    if (i < BB*DD) pooled[i] = 0.0f;
}

// ---------------------------------------------------------------------------
// msg kernel: 32 facts / 64 messages per block, 4 waves, LDS 32 KB.
// GEMM1: D1[n][m] (acc[4][4]); GEMM2: D2[d][m] (acc2[2][4]).
// Fully-unrolled k-loops + coalesced packed-weight loads for deep ILP.
// Builds node->msg bucket index (first 64 threads). Plain bf16 row stores.
// ---------------------------------------------------------------------------
__global__ __launch_bounds__(256, 4) void msg_kernel(
    const int* __restrict__ a0, const int* __restrict__ a1,
    const int* __restrict__ pidx, const float* __restrict__ bidir,
    const float* __restrict__ pos_emb, const float* __restrict__ pred_emb,
    const ushort* __restrict__ w1p, const float* __restrict__ b1,
    const ushort* __restrict__ w2p, const float* __restrict__ b2,
    ushort* __restrict__ msgbuf, int* __restrict__ cnt, ushort* __restrict__ idx16)
{
    __shared__ uint4 shm[2048];           // 32 KB union: xs (1536 u4) / h1 (2048 u4)

    const int tid = threadIdx.x;
    const int fbase = blockIdx.x * FPB;
    const int wid = tid >> 6, lane = tid & 63;
    const int lq = lane >> 4, lr = lane & 15;
    const int factL = lr >> 1, par = lr & 1;

    // ---- bucket build: one thread per message of this block ----
    if (tid < 2 * FPB) {
        const int i = blockIdx.x * (2 * FPB) + tid;    // global msg slot
        const int g = i >> 1, p = i & 1;
        const float w = p ? bidir[g] : 1.0f;
        if (w != 0.0f) {
            const int nid = ((g >> 12) << 10) + (p ? a0[g] : a1[g]);
            const int slot = atomicAdd(&cnt[nid], 1);
            if (slot < CAP) idx16[nid * CAP + slot] = (ushort)i;
        }
    }

    // ---- stage gathered inputs: fp32 load -> bf16 pack -> LDS (swizzled) ----
    #pragma unroll
    for (int it = 0; it < 6; ++it) {
        const int U = tid + it * 256;
        const int f = U / 48, u = U - 48 * f;
        const int seg = u >> 4, du = u & 15;
        const int g = fbase + f;
        const int row = (seg == 0) ? a0[g] : ((seg == 1) ? pidx[g] : a1[g]);
        const float* src = ((seg == 1) ? pred_emb : pos_emb) + row * DD + du * 8;
        const float4 x0 = *(const float4*)src;
        const float4 x1 = *(const float4*)(src + 4);
        uint4 t;
        t.x = f2bf(x0.x) | (f2bf(x0.y) << 16);
        t.y = f2bf(x0.z) | (f2bf(x0.w) << 16);
        t.z = f2bf(x1.x) | (f2bf(x1.y) << 16);
        t.w = f2bf(x1.z) | (f2bf(x1.w) << 16);
        shm[f * 48 + (u ^ (f & 7))] = t;
    }
    __syncthreads();

    // ---- GEMM1: D1[n][m], acc[nf][mf]; n = wid*64+nf*16+(lq*4+r), m col=lr ----
    f32x4 acc[4][4];
    #pragma unroll
    for (int nf = 0; nf < 4; ++nf)
        #pragma unroll
        for (int mf = 0; mf < 4; ++mf) acc[nf][mf] = (f32x4)0.0f;

    #pragma unroll
    for (int seg = 0; seg < 3; ++seg) {
        const int koff = par ? (seg == 0 ? 256 : (seg == 2 ? -256 : 0)) : 0;
        #pragma unroll
        for (int kk = 0; kk < 4; ++kk) {
            const int ks = seg * 4 + kk;
            const int kp = ks * 32 + lq * 8 + koff;
            const int uq = (kp >> 3) ^ factL;
            short8 xfrag[4];
            #pragma unroll
            for (int mf = 0; mf < 4; ++mf)
                xfrag[mf] = *(const short8*)&shm[(mf * 8 + factL) * 48 + uq];
            short8 wfrag[4];
            #pragma unroll
            for (int nf = 0; nf < 4; ++nf)
                wfrag[nf] = *(const short8*)(w1p + ((wid*4 + nf)*12 + ks)*512 + lr*32 + lq*8);
            #pragma unroll
            for (int nf = 0; nf < 4; ++nf)
                #pragma unroll
                for (int mf = 0; mf < 4; ++mf)
                    acc[nf][mf] = __builtin_amdgcn_mfma_f32_16x16x32_bf16(wfrag[nf], xfrag[mf], acc[nf][mf], 0, 0, 0);
        }
    }
    __syncthreads();   // xs dead; reuse LDS as h1[64][256] bf16 (swizzled)

    // ---- bias + gelu + packed h1 store (ds_write_b64) ----
    #pragma unroll
    for (int nf = 0; nf < 4; ++nf) {
        const float4 bj = *(const float4*)(b1 + wid * 64 + nf * 16 + lq * 4);
        #pragma unroll
        for (int mf = 0; mf < 4; ++mf) {
            const int m = mf * 16 + lr;
            uint2 t;
            t.x = f2bf(gelu_fast(acc[nf][mf][0] + bj.x)) |
                  (f2bf(gelu_fast(acc[nf][mf][1] + bj.y)) << 16);
            t.y = f2bf(gelu_fast(acc[nf][mf][2] + bj.z)) |
                  (f2bf(gelu_fast(acc[nf][mf][3] + bj.w)) << 16);
            const int col = wid * 128 + nf * 32 + lq * 8;   // byte col within 512B row
            const int byteoff = m * 512 + (((col >> 4) ^ (m & 15)) << 4) + (col & 15);
            *(uint2*)((char*)shm + byteoff) = t;
        }
    }
    __syncthreads();

    // ---- GEMM2: D2[d][m], acc2[nf][mf]; d = wid*32+nf*16+(lq*4+r) ----
    f32x4 acc2[2][4];
    #pragma unroll
    for (int nf = 0; nf < 2; ++nf)
        #pragma unroll
        for (int mf = 0; mf < 4; ++mf) acc2[nf][mf] = (f32x4)0.0f;

    #pragma unroll
    for (int ks = 0; ks < 8; ++ks) {
        short8 hfrag[4];
        #pragma unroll
        for (int mf = 0; mf < 4; ++mf) {
            const int m = mf * 16 + lr;
            hfrag[mf] = *(const short8*)((char*)shm + m * 512 + ((((ks * 4 + lq)) ^ (m & 15)) << 4));
        }
        short8 w2frag[2];
        #pragma unroll
        for (int nf = 0; nf < 2; ++nf)
            w2frag[nf] = *(const short8*)(w2p + ((wid*2 + nf)*8 + ks)*512 + lr*32 + lq*8);
        #pragma unroll
        for (int nf = 0; nf < 2; ++nf)
            #pragma unroll
            for (int mf = 0; mf < 4; ++mf)
                acc2[nf][mf] = __builtin_amdgcn_mfma_f32_16x16x32_bf16(w2frag[nf], hfrag[mf], acc2[nf][mf], 0, 0, 0);
    }

    // ---- epilogue: bias + bidir weight + plain bf16 stores (8B/lane) ----
    {
        float wgt_[4];
        #pragma unroll
        for (int mf = 0; mf < 4; ++mf) {
            const int g = fbase + mf * 8 + factL;
            wgt_[mf] = par ? bidir[g] : 1.0f;
        }
        #pragma unroll
        for (int nf = 0; nf < 2; ++nf) {
            const float4 bd = *(const float4*)(b2 + wid * 32 + nf * 16 + lq * 4);
            const int d0 = wid * 32 + nf * 16 + lq * 4;
            #pragma unroll
            for (int mf = 0; mf < 4; ++mf) {
                const int m = mf * 16 + lr;
                const float w = wgt_[mf];
                if (w != 0.0f) {
                    uint2 t;
                    t.x = f2bf((acc2[nf][mf][0] + bd.x) * w) |
                          (f2bf((acc2[nf][mf][1] + bd.y) * w) << 16);
                    t.y = f2bf((acc2[nf][mf][2] + bd.z) * w) |
                          (f2bf((acc2[nf][mf][3] + bd.w) * w) << 16);
                    *(uint2*)(msgbuf + (size_t)(fbase * 2 + m) * DD + d0) = t;
                }
            }
        }
    }
}

// ---------------------------------------------------------------------------
// Fused bucket-gather + LayerNorm + pool.  One wave per node, 4 nodes/block.
// ---------------------------------------------------------------------------
__global__ __launch_bounds__(256) void reduce_kernel(
    const float* __restrict__ pos_emb, const ushort* __restrict__ msgbuf,
    const int* __restrict__ cnt, const ushort* __restrict__ idx16,
    const float* __restrict__ ln_g, const float* __restrict__ ln_b,
    float* __restrict__ pooled)
{
    const int wave = threadIdx.x >> 6, lane = threadIdx.x & 63;
    const int nid = blockIdx.x * 4 + wave;
    const int s = nid & (SS - 1);
    const int b = (blockIdx.x * 4) >> 10;

    float2 h = *(const float2*)(pos_emb + s * DD + 2 * lane);
    int c = cnt[nid]; if (c > CAP) c = CAP;
    const ushort* bucket = idx16 + nid * CAP;
    for (int j = 0; j < c; ++j) {
        const uint mid = bucket[j];
        const uint u = *(const uint*)(msgbuf + (size_t)mid * DD + 2 * lane);
        h.x += bf2f(u & 0xffffu);
        h.y += bf2f(u >> 16);
    }

    float sum = h.x + h.y;
    #pragma unroll
    for (int o = 32; o > 0; o >>= 1) sum += __shfl_xor(sum, o);
    const float mu = sum * (1.0f / 128.0f);
    const float d0 = h.x - mu, d1 = h.y - mu;
    float sq = d0 * d0 + d1 * d1;
    #pragma unroll
    for (int o = 32; o > 0; o >>= 1) sq += __shfl_xor(sq, o);
    const float rstd = rsqrtf(sq * (1.0f / 128.0f) + 1e-5f);

    const float2 g2  = *(const float2*)(ln_g + 2 * lane);
    const float2 bb2 = *(const float2*)(ln_b + 2 * lane);
    const float p0 = d0 * rstd * g2.x + bb2.x;
    const float p1 = d1 * rstd * g2.y + bb2.y;

    __shared__ float red[4][128];
    red[wave][2 * lane]     = p0;
    red[wave][2 * lane + 1] = p1;
    __syncthreads();
    if (threadIdx.x < 128) {
        const float v = red[0][threadIdx.x] + red[1][threadIdx.x]
                      + red[2][threadIdx.x] + red[3][threadIdx.x];
        atomicAdd(&pooled[b * DD + threadIdx.x], v);
    }
}

// ---------------------------------------------------------------------------
// Latent head
// ---------------------------------------------------------------------------
__global__ __launch_bounds__(256) void head_kernel(
    const float* __restrict__ pooled,
    const float* __restrict__ lw1, const float* __restrict__ lb1,
    const float* __restrict__ lw2, const float* __restrict__ lb2,
    float* __restrict__ out)
{
    const int b = blockIdx.x;
    const int j = threadIdx.x;
    __shared__ float p[128];
    __shared__ float t1[256];
    if (j < 128) p[j] = pooled[b*DD + j] * (1.0f / (float)SS);
    __syncthreads();
    float acc = lb1[j];
    for (int k = 0; k < 128; ++k) acc += p[k] * lw1[k*256 + j];
    t1[j] = gelu_fast(acc);
    __syncthreads();
    float acc2 = lb2[j];
    for (int k = 0; k < 256; ++k) acc2 += t1[k] * lw2[k*256 + j];
    out[b*DLL + j] = acc2;
}

extern "C" void kernel_launch(void* const* d_in, const int* in_sizes, int n_in,
                              void* d_out, int out_size, void* d_ws, size_t ws_size,
                              hipStream_t stream) {
    const int*   a0       = (const int*)d_in[0];
    const int*   a1       = (const int*)d_in[1];
    const int*   pidx     = (const int*)d_in[2];
    const float* bidir    = (const float*)d_in[3];
    const float* pos_emb  = (const float*)d_in[4];
    const float* pred_emb = (const float*)d_in[5];
    const float* w1       = (const float*)d_in[6];
    const float* b1       = (const float*)d_in[7];
    const float* w2       = (const float*)d_in[8];
    const float* b2       = (const float*)d_in[9];
    const float* ln_g     = (const float*)d_in[10];
    const float* ln_b     = (const float*)d_in[11];
    const float* lw1      = (const float*)d_in[12];
    const float* lb1      = (const float*)d_in[13];
    const float* lw2      = (const float*)d_in[14];
    const float* lb2      = (const float*)d_in[15];

    char* ws = (char*)d_ws;
    // layout: end = 17,666,048 B (< 17,669,664 proven available in round 3)
    const size_t O_MSG  = 0;                             // 16 MB (NMSG*128 bf16)
    const size_t O_CNT  = 16777216;                      // 32 KB (int[NNODE])
    const size_t O_POOL = O_CNT + 32768;                 // 4 KB  (fp32[B*D])
    const size_t O_IDX  = O_POOL + 4096;                 // 576 KB (NNODE*CAP u16)
    const size_t O_W1P  = O_IDX + (size_t)NNODE*CAP*2;   // 192 KB
    const size_t O_W2P  = O_W1P + 196608;                // 64 KB

    ushort* msgbuf = (ushort*)(ws + O_MSG);
    int*    cnt    = (int*)(ws + O_CNT);
    float*  pooled = (float*)(ws + O_POOL);
    ushort* idx16  = (ushort*)(ws + O_IDX);
    ushort* w1p    = (ushort*)(ws + O_W1P);
    ushort* w2p    = (ushort*)(ws + O_W2P);

    prep_kernel<<<(N_PREP + 255) / 256, 256, 0, stream>>>(
        w1, w2, w1p, w2p, cnt, pooled);
    msg_kernel<<<NF / FPB, 256, 0, stream>>>(a0, a1, pidx, bidir,
        pos_emb, pred_emb, w1p, b1, w2p, b2, msgbuf, cnt, idx16);
    reduce_kernel<<<NNODE / 4, 256, 0, stream>>>(
        pos_emb, msgbuf, cnt, idx16, ln_g, ln_b, pooled);
    head_kernel<<<BB, 256, 0, stream>>>(pooled, lw1, lb1, lw2, lb2, (float*)d_out);
}